// Round 7
// baseline (243.285 us; speedup 1.0000x reference)
//
#include <hip/hip_runtime.h>
#include <hip/hip_bf16.h>

#define NN 4096
#define CAP 128   // max nnz per row tracked (binomial mean 41, sd 6.4)
#define KS 8      // k-splits for P-GEMM

typedef __attribute__((ext_vector_type(8))) short bf16x8;
typedef __attribute__((ext_vector_type(4))) float f32x4;

__device__ __forceinline__ float lrelu(float v) { return v >= 0.f ? v : 0.2f * v; }

// fp32 -> bf16 bits, round-to-nearest-even (inputs are finite)
__device__ __forceinline__ ushort f2bu(float f) {
    unsigned u = __float_as_uint(f);
    return (ushort)((u + 0x7FFFu + ((u >> 16) & 1u)) >> 16);
}

// ---------------------------------------------------------------------------
// K1: xwA1=x@W1[0], xwB1=x@W1[1], xwA2=x@W2[0], xwB2=x@W2[1], v0=x@W0,
//     a/b attention vectors, Bt = (x@W0)^T as bf16 for the P-GEMM.
// ---------------------------------------------------------------------------
__global__ __launch_bounds__(256) void k_prep(
    const float* __restrict__ x,
    const float* __restrict__ W1, const float* __restrict__ W2,
    const float* __restrict__ W0,
    const float* __restrict__ att1, const float* __restrict__ att2,
    float* __restrict__ xwA1, float* __restrict__ xwB1,
    float* __restrict__ xwA2, float* __restrict__ xwB2,
    float* __restrict__ a1, float* __restrict__ b1,
    float* __restrict__ a2, float* __restrict__ b2,
    __hip_bfloat16* __restrict__ Bt)
{
    __shared__ float wl[5120];   // W1(2048) W2(2048) W0(1024)
    __shared__ float xs[256];    // 8 rows x 32
    const int t = threadIdx.x;
    for (int i = t; i < 2048; i += 256) { wl[i] = W1[i]; wl[2048 + i] = W2[i]; }
    for (int i = t; i < 1024; i += 256) wl[4096 + i] = W0[i];
    const int rowBase = blockIdx.x * 8;
    xs[t] = x[rowBase * 32 + t];
    __syncthreads();

    const int o = t & 31, r = t >> 5;
    const int row = rowBase + r;
    const float* xr = &xs[r * 32];
    float vA1 = 0.f, vB1 = 0.f, vA2 = 0.f, vB2 = 0.f, v0 = 0.f;
#pragma unroll
    for (int f = 0; f < 32; ++f) {
        const float xv = xr[f];
        vA1 += xv * wl[f * 32 + o];
        vB1 += xv * wl[1024 + f * 32 + o];
        vA2 += xv * wl[2048 + f * 32 + o];
        vB2 += xv * wl[3072 + f * 32 + o];
        v0  += xv * wl[4096 + f * 32 + o];
    }
    xwA1[row * 32 + o] = vA1;
    xwB1[row * 32 + o] = vB1;
    xwA2[row * 32 + o] = vA2;
    xwB2[row * 32 + o] = vB2;
    ((ushort*)Bt)[(size_t)o * NN + row] = f2bu(v0);

    float pa1 = vA1 * att1[o]      + vB1 * att1[32 + o];
    float pb1 = vA1 * att1[64 + o] + vB1 * att1[96 + o];
    float pa2 = vA2 * att2[o]      + vB2 * att2[32 + o];
    float pb2 = vA2 * att2[64 + o] + vB2 * att2[96 + o];
#pragma unroll
    for (int m = 1; m <= 16; m <<= 1) {
        pa1 += __shfl_xor(pa1, m); pb1 += __shfl_xor(pb1, m);
        pa2 += __shfl_xor(pa2, m); pb2 += __shfl_xor(pb2, m);
    }
    if (o == 0) { a1[row] = pa1; b1[row] = pb1; a2[row] = pa2; b2[row] = pb2; }
}

// ---------------------------------------------------------------------------
// K2 (k_work): grid-partition fusion. Every 9th block = one P-GEMM tile
// (single-buffered MFMA, 24 KB LDS); the other 4096 = one k_csr row each
// (stream + ballot compaction). The GEMM's MFMA/LDS work hides inside the
// stream's memory stalls; csr occupancy stays >=6 blocks/CU at 24 KB.
// ---------------------------------------------------------------------------
__global__ __launch_bounds__(256) void k_work(
    const float* __restrict__ Ld, const float* __restrict__ Lu,
    const float* __restrict__ P, const ushort* __restrict__ Bt,
    int2* __restrict__ csrv, int* __restrict__ cntArr,
    float* __restrict__ partial)
{
    __shared__ ushort sA[16 * 64 * 8];   // 16 KB
    __shared__ ushort sB[8 * 64 * 8];    //  8 KB
    const int t = threadIdx.x;
    const int lane = t & 63, w = t >> 6;
    const int bx = blockIdx.x;

    if (bx % 9 == 0) {
        // ---------------- P-GEMM tile ----------------
        const int bp = bx / 9;               // 0..511
        const int row0 = (bp & 63) * 64;
        const int ks = bp >> 6;              // 0..7
        const float4*  P4  = (const float4*)P;
        const ushort4* Bt4 = (const ushort4*)Bt;
        f32x4 acc0 = {0.f, 0.f, 0.f, 0.f};
        f32x4 acc1 = {0.f, 0.f, 0.f, 0.f};

        for (int c = 0; c < 4; ++c) {
            const int kc4 = (ks * 512 + c * 128) >> 2;
#pragma unroll
            for (int j = 0; j < 8; ++j) {
                const int i = t + 256 * j;
                const int row = i >> 5, q = i & 31;
                const float4 v = P4[(size_t)(row0 + row) * 1024 + kc4 + q];
                ushort4 u;
                u.x = f2bu(v.x); u.y = f2bu(v.y); u.z = f2bu(v.z); u.w = f2bu(v.w);
                const int wi = row >> 4, m = row & 15;
                const int kk = q >> 3, quad = (q >> 1) & 3, jj = q & 1;
                *(ushort4*)&sA[(((wi * 4 + kk) * 64) + quad * 16 + m) * 8 + jj * 4] = u;
            }
#pragma unroll
            for (int j = 0; j < 4; ++j) {
                const int i = t + 256 * j;
                const int o = i >> 5, q = i & 31;
                const ushort4 u = Bt4[(size_t)o * 1024 + kc4 + q];
                const int nt = o >> 4, n = o & 15;
                const int kk = q >> 3, quad = (q >> 1) & 3, jj = q & 1;
                *(ushort4*)&sB[(((kk * 2 + nt) * 64) + quad * 16 + n) * 8 + jj * 4] = u;
            }
            __syncthreads();
            const ushort* pa = &sA[(w * 4) * 64 * 8 + lane * 8];
            const ushort* pb = &sB[lane * 8];
#pragma unroll
            for (int kk = 0; kk < 4; ++kk) {
                const bf16x8 a  = *(const bf16x8*)(pa + kk * 512);
                const bf16x8 b0 = *(const bf16x8*)(pb + kk * 1024);
                const bf16x8 b1 = *(const bf16x8*)(pb + kk * 1024 + 512);
                acc0 = __builtin_amdgcn_mfma_f32_16x16x32_bf16(a, b0, acc0, 0, 0, 0);
                acc1 = __builtin_amdgcn_mfma_f32_16x16x32_bf16(a, b1, acc1, 0, 0, 0);
            }
            __syncthreads();
        }
        const int m = lane & 15, quad = lane >> 4;
        float* out = partial + ((size_t)ks * NN + row0 + w * 16 + quad * 4) * 32;
#pragma unroll
        for (int r = 0; r < 4; ++r) {
            out[r * 32 + m]      = acc0[r];
            out[r * 32 + 16 + m] = acc1[r];
        }
    } else {
        // ---------------- CSR row ----------------
        const int row = bx - 1 - bx / 9;     // 0..4095
        int* wcnt = (int*)sA;                // alias first 64 B

        float4 v[8];
        const float4* A4 = (const float4*)(Ld + (size_t)row * NN);
        const float4* B4 = (const float4*)(Lu + (size_t)row * NN);
#pragma unroll
        for (int it = 0; it < 4; ++it) { v[it] = A4[it * 256 + t]; v[4 + it] = B4[it * 256 + t]; }

        const unsigned long long lt = (1ull << lane) - 1ull;
#pragma unroll
        for (int br = 0; br < 2; ++br) {
            int2* out = csrv + ((size_t)br * NN + row) * CAP;
            int tots[4];
#pragma unroll
            for (int it = 0; it < 4; ++it) {
                const float4 fv = v[br * 4 + it];
                tots[it] = __popcll(__ballot(fv.x != 0.f)) + __popcll(__ballot(fv.y != 0.f))
                         + __popcll(__ballot(fv.z != 0.f)) + __popcll(__ballot(fv.w != 0.f));
            }
            __syncthreads();
            if (lane == 0) {
                int4 tv; tv.x = tots[0]; tv.y = tots[1]; tv.z = tots[2]; tv.w = tots[3];
                *(int4*)&wcnt[w * 4] = tv;
            }
            __syncthreads();
            const int4 ca = *(const int4*)&wcnt[0];
            const int4 cb = *(const int4*)&wcnt[4];
            const int4 cc = *(const int4*)&wcnt[8];
            const int4 cd = *(const int4*)&wcnt[12];
            const int cs[16] = {ca.x, ca.y, ca.z, ca.w, cb.x, cb.y, cb.z, cb.w,
                                cc.x, cc.y, cc.z, cc.w, cd.x, cd.y, cd.z, cd.w};
            int total = 0;
#pragma unroll
            for (int k2 = 0; k2 < 16; ++k2) total += cs[k2];
            int base = 0;
#pragma unroll
            for (int k2 = 0; k2 < 16; ++k2) base += (k2 < (w << 2)) ? cs[k2] : 0;
            const int cnt  = min(total, CAP);
            const int cp16 = min((cnt + 15) & ~15, CAP);

#pragma unroll
            for (int it = 0; it < 4; ++it) {
                const float4 fv = v[br * 4 + it];
                const unsigned long long m0 = __ballot(fv.x != 0.f);
                const unsigned long long m1 = __ballot(fv.y != 0.f);
                const unsigned long long m2 = __ballot(fv.z != 0.f);
                const unsigned long long m3 = __ballot(fv.w != 0.f);
                const int p0 = __popcll(m0), p1 = __popcll(m1), p2 = __popcll(m2);
                const int c0 = (it * 256 + t) * 4;
                int s;
                s = base + __popcll(m0 & lt);
                if (fv.x != 0.f && s < CAP) { int2 e; e.x = c0;     e.y = __float_as_int(fv.x); out[s] = e; }
                s = base + p0 + __popcll(m1 & lt);
                if (fv.y != 0.f && s < CAP) { int2 e; e.x = c0 + 1; e.y = __float_as_int(fv.y); out[s] = e; }
                s = base + p0 + p1 + __popcll(m2 & lt);
                if (fv.z != 0.f && s < CAP) { int2 e; e.x = c0 + 2; e.y = __float_as_int(fv.z); out[s] = e; }
                s = base + p0 + p1 + p2 + __popcll(m3 & lt);
                if (fv.w != 0.f && s < CAP) { int2 e; e.x = c0 + 3; e.y = __float_as_int(fv.w); out[s] = e; }
                base += p0 + p1 + p2 + __popcll(m3);
            }
            if (t >= cnt && t < cp16) { int2 e; e.x = 0; e.y = 0; out[t] = e; }
            if (t == 0) cntArr[br * NN + row] = cnt;
        }
    }
}

// ---------------------------------------------------------------------------
// K3 (k_gather): wave per (row,branch). Sequential int2 list load -> LDS,
// batched gather of xwB (L2-resident), u[row] = xwA[row] + sum.
// ---------------------------------------------------------------------------
__global__ __launch_bounds__(256) void k_gather(
    const int2* __restrict__ csrv, const int* __restrict__ cntArr,
    const float* __restrict__ xwB1, const float* __restrict__ xwB2,
    const float* __restrict__ xwA1, const float* __restrict__ xwA2,
    float* __restrict__ u1, float* __restrict__ u2)
{
    __shared__ int2 sle[4][CAP];
    const int w = threadIdx.x >> 6, lane = threadIdx.x & 63;
    const int row = blockIdx.x * 4 + w;
    const int br  = blockIdx.y;
    const float* xwB = br ? xwB2 : xwB1;
    const float* xwA = br ? xwA2 : xwA1;
    float* u = br ? u2 : u1;

    const int cnt  = cntArr[br * NN + row];
    const int cp16 = min((cnt + 15) & ~15, CAP);
    const int2* ci = csrv + ((size_t)br * NN + row) * CAP;
    int2* se = sle[w];
    if (lane < cp16)      se[lane]      = ci[lane];
    if (lane + 64 < cp16) se[lane + 64] = ci[lane + 64];
    // wave-private LDS segment; same-wave DS ordering + compiler waits

    const int o = lane & 31, g = lane >> 5;
    float acc = 0.f;
    const int nb = cp16 >> 3;     // 8 slots/batch, 4 per half (broadcast reads)
    for (int j = 0; j < nb; ++j) {
        float wv[4], xv[4];
#pragma unroll
        for (int q = 0; q < 4; ++q) {
            const int2 e = se[8 * j + 2 * q + g];
            wv[q] = __int_as_float(e.y);
            xv[q] = xwB[(size_t)e.x * 32 + o];
        }
#pragma unroll
        for (int q = 0; q < 4; ++q) acc += wv[q] * xv[q];
    }
    acc += __shfl_xor(acc, 32);
    if (lane < 32) u[(size_t)row * 32 + o] = acc + xwA[(size_t)row * 32 + o];
}

// ---------------------------------------------------------------------------
// K4 (k_attn2): wave per row, BOTH branches sequentially, then fold in the
// KS partials and write d_out directly (k_combine eliminated).
// ---------------------------------------------------------------------------
__global__ __launch_bounds__(256) void k_attn2(
    const int2* __restrict__ csrv, const int* __restrict__ cntArr,
    const float* __restrict__ a1, const float* __restrict__ b1,
    const float* __restrict__ a2, const float* __restrict__ b2,
    const float* __restrict__ u1, const float* __restrict__ u2,
    const float* __restrict__ partial, float* __restrict__ outp)
{
    __shared__ float sw[4 * CAP];
    __shared__ int   sci[4 * CAP];
    const int w = threadIdx.x >> 6, lane = threadIdx.x & 63;
    const int row = blockIdx.x * 4 + w;
    float* swg = sw + w * CAP;
    int*   scg = sci + w * CAP;
    const int o = lane & 31, h = lane >> 5;
    float total = 0.f;

#pragma unroll
    for (int br = 0; br < 2; ++br) {
        const float* aA = br ? a2 : a1;
        const float* bA = br ? b2 : b1;
        const float* U  = br ? u2 : u1;
        const int cnt = cntArr[br * NN + row];
        const int cp16 = min((cnt + 15) & ~15, CAP);
        const float ai = aA[row];
        const int2* ci = csrv + ((size_t)br * NN + row) * CAP;

        int id0 = 0, id1 = 0;
        if (lane < cp16)      id0 = ci[lane].x;
        if (lane + 64 < cp16) id1 = ci[lane + 64].x;
        float e0 = (lane < cnt)      ? lrelu(ai + bA[id0]) : -1e30f;
        float e1 = (lane + 64 < cnt) ? lrelu(ai + bA[id1]) : -1e30f;
        float lmax = fmaxf(e0, e1);
#pragma unroll
        for (int m = 1; m <= 32; m <<= 1) lmax = fmaxf(lmax, __shfl_xor(lmax, m));
        const float w0 = __expf(e0 - lmax), w1 = __expf(e1 - lmax);
        float ssum = w0 + w1;
#pragma unroll
        for (int m = 1; m <= 32; m <<= 1) ssum += __shfl_xor(ssum, m);
        swg[lane] = w0; swg[lane + 64] = w1;
        scg[lane] = id0; scg[lane + 64] = id1;
        // wave-private LDS segment; same-wave ordering

        float acc = 0.f;
        const int nb = cp16 >> 3;    // 8 slots/batch, 4 per half
        if (cnt > 0) {
            float wgA[4], uvA[4];
#pragma unroll
            for (int q = 0; q < 4; ++q) {
                const int s = h + 2 * q;
                wgA[q] = swg[s];
                uvA[q] = U[(size_t)scg[s] * 32 + o];
            }
            for (int j = 1; j < nb; ++j) {
                float wgB[4], uvB[4];
#pragma unroll
                for (int q = 0; q < 4; ++q) {
                    const int s = h + 8 * j + 2 * q;
                    wgB[q] = swg[s];
                    uvB[q] = U[(size_t)scg[s] * 32 + o];
                }
#pragma unroll
                for (int q = 0; q < 4; ++q) acc += wgA[q] * uvA[q];
#pragma unroll
                for (int q = 0; q < 4; ++q) { wgA[q] = wgB[q]; uvA[q] = uvB[q]; }
            }
#pragma unroll
            for (int q = 0; q < 4; ++q) acc += wgA[q] * uvA[q];
        }
        acc += __shfl_xor(acc, 32);
        if (cnt > 0) total += acc / ssum;
    }

    if (lane < 32) {
#pragma unroll
        for (int p = 0; p < KS; ++p)
            total += partial[(size_t)p * NN * 32 + (size_t)row * 32 + o];
        outp[(size_t)row * 32 + o] = total;
    }
}

extern "C" void kernel_launch(void* const* d_in, const int* in_sizes, int n_in,
                              void* d_out, int out_size, void* d_ws, size_t ws_size,
                              hipStream_t stream) {
    (void)in_sizes; (void)n_in; (void)out_size; (void)ws_size;
    const float* x    = (const float*)d_in[0];
    const float* Ld   = (const float*)d_in[1];
    const float* Lu   = (const float*)d_in[2];
    const float* P    = (const float*)d_in[3];
    const float* W1   = (const float*)d_in[4];
    const float* W2   = (const float*)d_in[5];
    const float* W0   = (const float*)d_in[6];
    const float* att1 = (const float*)d_in[7];
    const float* att2 = (const float*)d_in[8];

    float* ws = (float*)d_ws;
    float* xwA1 = ws;                 // 131072 each
    float* xwB1 = ws + 131072;
    float* xwA2 = ws + 262144;
    float* xwB2 = ws + 393216;
    float* u1   = ws + 524288;        // xwA + L@xwB (fused)
    float* u2   = ws + 655360;
    float* a1   = ws + 786432;        // 4096 each
    float* b1   = ws + 790528;
    float* a2   = ws + 794624;
    float* b2   = ws + 798720;
    float* partial = ws + 802816;           // KS*131072 floats = 4 MB
    __hip_bfloat16* Bt = (__hip_bfloat16*)(ws + 1851392);   // 131072 bf16
    int2* csrv = (int2*)(ws + 1916928);     // 2*4096*128 int2 = 8 MB
    int*  cnt  = (int*)(ws + 4014080);      // 8192 ints

    k_prep<<<512, 256, 0, stream>>>(x, W1, W2, W0, att1, att2,
                                    xwA1, xwB1, xwA2, xwB2, a1, b1, a2, b2, Bt);
    k_work<<<4608, 256, 0, stream>>>(Ld, Lu, P, (const ushort*)Bt,
                                     csrv, cnt, partial);
    k_gather<<<dim3(NN / 4, 2), 256, 0, stream>>>(csrv, cnt, xwB1, xwB2,
                                                  xwA1, xwA2, u1, u2);
    k_attn2<<<NN / 4, 256, 0, stream>>>(csrv, cnt, a1, b1, a2, b2,
                                        u1, u2, partial, (float*)d_out);
}

// Round 8
// 236.860 us; speedup vs baseline: 1.0271x; 1.0271x over previous
//
#include <hip/hip_runtime.h>
#include <hip/hip_bf16.h>

#define NN 4096
#define CAP 128   // max nnz per row tracked (binomial mean 41, sd 6.4)
#define KS 8      // k-splits for P-GEMM

typedef __attribute__((ext_vector_type(8))) short bf16x8;
typedef __attribute__((ext_vector_type(4))) float f32x4;

__device__ __forceinline__ float lrelu(float v) { return v >= 0.f ? v : 0.2f * v; }

// fp32 -> bf16 bits, round-to-nearest-even (inputs are finite)
__device__ __forceinline__ ushort f2bu(float f) {
    unsigned u = __float_as_uint(f);
    return (ushort)((u + 0x7FFFu + ((u >> 16) & 1u)) >> 16);
}

// ---------------------------------------------------------------------------
// K1: xwA1=x@W1[0], xwB1=x@W1[1], xwA2=x@W2[0], xwB2=x@W2[1], v0=x@W0,
//     a/b attention vectors, Bt = (x@W0)^T as bf16 for the P-GEMM.
// ---------------------------------------------------------------------------
__global__ __launch_bounds__(256) void k_prep(
    const float* __restrict__ x,
    const float* __restrict__ W1, const float* __restrict__ W2,
    const float* __restrict__ W0,
    const float* __restrict__ att1, const float* __restrict__ att2,
    float* __restrict__ xwA1, float* __restrict__ xwB1,
    float* __restrict__ xwA2, float* __restrict__ xwB2,
    float* __restrict__ a1, float* __restrict__ b1,
    float* __restrict__ a2, float* __restrict__ b2,
    __hip_bfloat16* __restrict__ Bt)
{
    __shared__ float wl[5120];   // W1(2048) W2(2048) W0(1024)
    __shared__ float xs[256];    // 8 rows x 32
    const int t = threadIdx.x;
    for (int i = t; i < 2048; i += 256) { wl[i] = W1[i]; wl[2048 + i] = W2[i]; }
    for (int i = t; i < 1024; i += 256) wl[4096 + i] = W0[i];
    const int rowBase = blockIdx.x * 8;
    xs[t] = x[rowBase * 32 + t];
    __syncthreads();

    const int o = t & 31, r = t >> 5;
    const int row = rowBase + r;
    const float* xr = &xs[r * 32];
    float vA1 = 0.f, vB1 = 0.f, vA2 = 0.f, vB2 = 0.f, v0 = 0.f;
#pragma unroll
    for (int f = 0; f < 32; ++f) {
        const float xv = xr[f];
        vA1 += xv * wl[f * 32 + o];
        vB1 += xv * wl[1024 + f * 32 + o];
        vA2 += xv * wl[2048 + f * 32 + o];
        vB2 += xv * wl[3072 + f * 32 + o];
        v0  += xv * wl[4096 + f * 32 + o];
    }
    xwA1[row * 32 + o] = vA1;
    xwB1[row * 32 + o] = vB1;
    xwA2[row * 32 + o] = vA2;
    xwB2[row * 32 + o] = vB2;
    ((ushort*)Bt)[(size_t)o * NN + row] = f2bu(v0);

    float pa1 = vA1 * att1[o]      + vB1 * att1[32 + o];
    float pb1 = vA1 * att1[64 + o] + vB1 * att1[96 + o];
    float pa2 = vA2 * att2[o]      + vB2 * att2[32 + o];
    float pb2 = vA2 * att2[64 + o] + vB2 * att2[96 + o];
#pragma unroll
    for (int m = 1; m <= 16; m <<= 1) {
        pa1 += __shfl_xor(pa1, m); pb1 += __shfl_xor(pb1, m);
        pa2 += __shfl_xor(pa2, m); pb2 += __shfl_xor(pb2, m);
    }
    if (o == 0) { a1[row] = pa1; b1[row] = pb1; a2[row] = pa2; b2[row] = pb2; }
}

// ---------------------------------------------------------------------------
// K2 (k_csr2): MLP probe — 2 rows/block, 16 float4 in flight per wave (64
// data VGPRs) before the first barrier drain. Pure stream + two-phase ballot
// compaction; (col,valbits) lists padded to x16 with {0,0} sentinels.
// ---------------------------------------------------------------------------
__global__ __launch_bounds__(256) void k_csr2(
    const float* __restrict__ Ld, const float* __restrict__ Lu,
    int2* __restrict__ csrv, int* __restrict__ cntArr)
{
    const int r0 = blockIdx.x * 2;
    const int t = threadIdx.x, lane = t & 63, w = t >> 6;
    __shared__ int wcnt[16];

    // 16 float4 loads issued back-to-back: combo c (0..3) = {Ld r0, Lu r0,
    // Ld r1, Lu r1}, 4 float4 each.
    float4 v[16];
    {
        const float4* A0 = (const float4*)(Ld + (size_t)r0 * NN);
        const float4* B0 = (const float4*)(Lu + (size_t)r0 * NN);
        const float4* A1 = (const float4*)(Ld + (size_t)(r0 + 1) * NN);
        const float4* B1 = (const float4*)(Lu + (size_t)(r0 + 1) * NN);
#pragma unroll
        for (int it = 0; it < 4; ++it) {
            v[it]      = A0[it * 256 + t];
            v[4 + it]  = B0[it * 256 + t];
            v[8 + it]  = A1[it * 256 + t];
            v[12 + it] = B1[it * 256 + t];
        }
    }

    const unsigned long long lt = (1ull << lane) - 1ull;
#pragma unroll
    for (int c = 0; c < 4; ++c) {
        const int row = r0 + (c >> 1);
        const int br  = c & 1;
        int2* out = csrv + ((size_t)br * NN + row) * CAP;
        int tots[4];
#pragma unroll
        for (int it = 0; it < 4; ++it) {
            const float4 fv = v[c * 4 + it];
            tots[it] = __popcll(__ballot(fv.x != 0.f)) + __popcll(__ballot(fv.y != 0.f))
                     + __popcll(__ballot(fv.z != 0.f)) + __popcll(__ballot(fv.w != 0.f));
        }
        __syncthreads();
        if (lane == 0) {
            int4 tv; tv.x = tots[0]; tv.y = tots[1]; tv.z = tots[2]; tv.w = tots[3];
            *(int4*)&wcnt[w * 4] = tv;
        }
        __syncthreads();
        const int4 ca = *(const int4*)&wcnt[0];
        const int4 cb = *(const int4*)&wcnt[4];
        const int4 cc = *(const int4*)&wcnt[8];
        const int4 cd = *(const int4*)&wcnt[12];
        const int cs[16] = {ca.x, ca.y, ca.z, ca.w, cb.x, cb.y, cb.z, cb.w,
                            cc.x, cc.y, cc.z, cc.w, cd.x, cd.y, cd.z, cd.w};
        int total = 0;
#pragma unroll
        for (int k2 = 0; k2 < 16; ++k2) total += cs[k2];
        int base = 0;
#pragma unroll
        for (int k2 = 0; k2 < 16; ++k2) base += (k2 < (w << 2)) ? cs[k2] : 0;
        const int cnt  = min(total, CAP);
        const int cp16 = min((cnt + 15) & ~15, CAP);

#pragma unroll
        for (int it = 0; it < 4; ++it) {
            const float4 fv = v[c * 4 + it];
            const unsigned long long m0 = __ballot(fv.x != 0.f);
            const unsigned long long m1 = __ballot(fv.y != 0.f);
            const unsigned long long m2 = __ballot(fv.z != 0.f);
            const unsigned long long m3 = __ballot(fv.w != 0.f);
            const int p0 = __popcll(m0), p1 = __popcll(m1), p2 = __popcll(m2);
            const int c0 = (it * 256 + t) * 4;
            int s;
            s = base + __popcll(m0 & lt);
            if (fv.x != 0.f && s < CAP) { int2 e; e.x = c0;     e.y = __float_as_int(fv.x); out[s] = e; }
            s = base + p0 + __popcll(m1 & lt);
            if (fv.y != 0.f && s < CAP) { int2 e; e.x = c0 + 1; e.y = __float_as_int(fv.y); out[s] = e; }
            s = base + p0 + p1 + __popcll(m2 & lt);
            if (fv.z != 0.f && s < CAP) { int2 e; e.x = c0 + 2; e.y = __float_as_int(fv.z); out[s] = e; }
            s = base + p0 + p1 + p2 + __popcll(m3 & lt);
            if (fv.w != 0.f && s < CAP) { int2 e; e.x = c0 + 3; e.y = __float_as_int(fv.w); out[s] = e; }
            base += p0 + p1 + p2 + __popcll(m3);
        }
        if (t >= cnt && t < cp16) { int2 e; e.x = 0; e.y = 0; out[t] = e; }
        if (t == 0) cntArr[br * NN + row] = cnt;
    }
}

// ---------------------------------------------------------------------------
// K3 (k_gather2): wave per (row,branch). Loads list, computes
// u[row] = xwA[row] + L[row,:]@xwB, AND the softmax: overwrites csrv[s].y
// with the normalized weight exp(e_s - m)/ssum (0 for sentinels). After
// this kernel the raw L values are dead and k_accum is a pure gather.
// ---------------------------------------------------------------------------
__global__ __launch_bounds__(256) void k_gather2(
    int2* __restrict__ csrv, const int* __restrict__ cntArr,
    const float* __restrict__ xwB1, const float* __restrict__ xwB2,
    const float* __restrict__ xwA1, const float* __restrict__ xwA2,
    const float* __restrict__ a1, const float* __restrict__ b1,
    const float* __restrict__ a2, const float* __restrict__ b2,
    float* __restrict__ u1, float* __restrict__ u2)
{
    __shared__ int2 sle[4][CAP];
    const int w = threadIdx.x >> 6, lane = threadIdx.x & 63;
    const int row = blockIdx.x * 4 + w;
    const int br  = blockIdx.y;
    const float* xwB = br ? xwB2 : xwB1;
    const float* xwA = br ? xwA2 : xwA1;
    const float* aA  = br ? a2 : a1;
    const float* bA  = br ? b2 : b1;
    float* u = br ? u2 : u1;

    const int cnt  = cntArr[br * NN + row];
    const int cp16 = min((cnt + 15) & ~15, CAP);
    int2* ci = csrv + ((size_t)br * NN + row) * CAP;
    int2* se = sle[w];
    int2 l0 = {0, 0}, l1 = {0, 0};
    if (lane < cp16)      { l0 = ci[lane];      se[lane]      = l0; }
    if (lane + 64 < cp16) { l1 = ci[lane + 64]; se[lane + 64] = l1; }
    // wave-private LDS segment; same-wave DS ordering + compiler waits

    // softmax weights (slots lane, lane+64)
    const float ai = aA[row];
    const float e0 = (lane < cnt)      ? lrelu(ai + bA[l0.x]) : -1e30f;
    const float e1 = (lane + 64 < cnt) ? lrelu(ai + bA[l1.x]) : -1e30f;
    float lmax = fmaxf(e0, e1);
#pragma unroll
    for (int m = 1; m <= 32; m <<= 1) lmax = fmaxf(lmax, __shfl_xor(lmax, m));
    const float w0 = __expf(e0 - lmax), w1 = __expf(e1 - lmax);
    float ssum = w0 + w1;
#pragma unroll
    for (int m = 1; m <= 32; m <<= 1) ssum += __shfl_xor(ssum, m);
    const float inv = (cnt > 0) ? 1.f / ssum : 0.f;
    if (lane < cp16)      { l0.y = __float_as_int((lane < cnt)      ? w0 * inv : 0.f); ci[lane]      = l0; }
    if (lane + 64 < cp16) { l1.y = __float_as_int((lane + 64 < cnt) ? w1 * inv : 0.f); ci[lane + 64] = l1; }

    // y-gather with raw values (still in LDS copy)
    const int o = lane & 31, g = lane >> 5;
    float acc = 0.f;
    const int nb = cp16 >> 3;     // 8 slots/batch, 4 per half (broadcast reads)
    for (int j = 0; j < nb; ++j) {
        float wv[4], xv[4];
#pragma unroll
        for (int q = 0; q < 4; ++q) {
            const int2 e = se[8 * j + 2 * q + g];
            wv[q] = __int_as_float(e.y);
            xv[q] = xwB[(size_t)e.x * 32 + o];
        }
#pragma unroll
        for (int q = 0; q < 4; ++q) acc += wv[q] * xv[q];
    }
    acc += __shfl_xor(acc, 32);
    if (lane < 32) u[(size_t)row * 32 + o] = acc + xwA[(size_t)row * 32 + o];
}

// ---------------------------------------------------------------------------
// K4 (k_accum): wave per row. Pure weighted gather of U for both branches
// (weights pre-normalized in csrv), fold in KS partials, write d_out.
// ---------------------------------------------------------------------------
__global__ __launch_bounds__(256) void k_accum(
    const int2* __restrict__ csrv, const int* __restrict__ cntArr,
    const float* __restrict__ u1, const float* __restrict__ u2,
    const float* __restrict__ partial, float* __restrict__ outp)
{
    __shared__ int2 sle[4][2 * CAP];
    const int w = threadIdx.x >> 6, lane = threadIdx.x & 63;
    const int row = blockIdx.x * 4 + w;
    const int o = lane & 31, g = lane >> 5;
    int2* se = sle[w];
    float total = 0.f;

    int cp[2];
#pragma unroll
    for (int br = 0; br < 2; ++br) {
        const int cnt = cntArr[br * NN + row];
        cp[br] = min((cnt + 15) & ~15, CAP);
        const int2* ci = csrv + ((size_t)br * NN + row) * CAP;
        if (lane < cp[br])      se[br * CAP + lane]      = ci[lane];
        if (lane + 64 < cp[br]) se[br * CAP + lane + 64] = ci[lane + 64];
    }
    // wave-private LDS segment; same-wave ordering

#pragma unroll
    for (int br = 0; br < 2; ++br) {
        const float* U = br ? u2 : u1;
        float acc = 0.f;
        const int nb = cp[br] >> 3;
        for (int j = 0; j < nb; ++j) {
            float wv[4], uv[4];
#pragma unroll
            for (int q = 0; q < 4; ++q) {
                const int2 e = se[br * CAP + 8 * j + 2 * q + g];
                wv[q] = __int_as_float(e.y);
                uv[q] = U[(size_t)e.x * 32 + o];
            }
#pragma unroll
            for (int q = 0; q < 4; ++q) acc += wv[q] * uv[q];
        }
        acc += __shfl_xor(acc, 32);
        total += acc;
    }

    if (lane < 32) {
#pragma unroll
        for (int p = 0; p < KS; ++p)
            total += partial[(size_t)p * NN * 32 + (size_t)row * 32 + o];
        outp[(size_t)row * 32 + o] = total;
    }
}

// ---------------------------------------------------------------------------
// K5 (MFMA): partial[ks] = P[:, krange] @ B[krange, :]
// Block = 64 rows x 32 cols x 512 k; 4 chunks of 128 k, double-buffered LDS.
// ---------------------------------------------------------------------------
__global__ __launch_bounds__(256) void k_pgemm(
    const float* __restrict__ P, const ushort* __restrict__ Bt,
    float* __restrict__ partial)
{
    __shared__ ushort sA[2][16 * 64 * 8];
    __shared__ ushort sB[2][8 * 64 * 8];
    const int t = threadIdx.x;
    const int row0 = blockIdx.x * 64;
    const int ks = blockIdx.y;
    const float4*  P4  = (const float4*)P;
    const ushort4* Bt4 = (const ushort4*)Bt;

    const int lane = t & 63, w = t >> 6;

    f32x4 acc0 = {0.f, 0.f, 0.f, 0.f};
    f32x4 acc1 = {0.f, 0.f, 0.f, 0.f};

    auto stageA = [&](int c, int buf) {
        const int kc4 = (ks * 512 + c * 128) >> 2;
#pragma unroll
        for (int j = 0; j < 8; ++j) {
            const int i = t + 256 * j;
            const int row = i >> 5, q = i & 31;
            const float4 v = P4[(size_t)(row0 + row) * 1024 + kc4 + q];
            ushort4 u;
            u.x = f2bu(v.x); u.y = f2bu(v.y); u.z = f2bu(v.z); u.w = f2bu(v.w);
            const int wi = row >> 4, m = row & 15;
            const int kk = q >> 3, quad = (q >> 1) & 3, jj = q & 1;
            *(ushort4*)&sA[buf][(((wi * 4 + kk) * 64) + quad * 16 + m) * 8 + jj * 4] = u;
        }
    };
    auto stageB = [&](int c, int buf) {
        const int kc4 = (ks * 512 + c * 128) >> 2;
#pragma unroll
        for (int j = 0; j < 4; ++j) {
            const int i = t + 256 * j;
            const int o = i >> 5, q = i & 31;
            const ushort4 u = Bt4[(size_t)o * 1024 + kc4 + q];
            const int nt = o >> 4, n = o & 15;
            const int kk = q >> 3, quad = (q >> 1) & 3, jj = q & 1;
            *(ushort4*)&sB[buf][(((kk * 2 + nt) * 64) + quad * 16 + n) * 8 + jj * 4] = u;
        }
    };
    auto compute = [&](int buf) {
        const ushort* pa = &sA[buf][(w * 4) * 64 * 8 + lane * 8];
        const ushort* pb = &sB[buf][lane * 8];
#pragma unroll
        for (int kk = 0; kk < 4; ++kk) {
            const bf16x8 a  = *(const bf16x8*)(pa + kk * 512);
            const bf16x8 b0 = *(const bf16x8*)(pb + kk * 1024);
            const bf16x8 b1 = *(const bf16x8*)(pb + kk * 1024 + 512);
            acc0 = __builtin_amdgcn_mfma_f32_16x16x32_bf16(a, b0, acc0, 0, 0, 0);
            acc1 = __builtin_amdgcn_mfma_f32_16x16x32_bf16(a, b1, acc1, 0, 0, 0);
        }
    };

    stageA(0, 0); stageB(0, 0);
    __syncthreads();
    for (int c = 0; c < 4; ++c) {
        if (c < 3) { stageA(c + 1, (c + 1) & 1); stageB(c + 1, (c + 1) & 1); }
        compute(c & 1);
        __syncthreads();
    }

    const int m = lane & 15, quad = lane >> 4;
    float* out = partial + ((size_t)ks * NN + row0 + w * 16 + quad * 4) * 32;
#pragma unroll
    for (int r = 0; r < 4; ++r) {
        out[r * 32 + m]      = acc0[r];
        out[r * 32 + 16 + m] = acc1[r];
    }
}

extern "C" void kernel_launch(void* const* d_in, const int* in_sizes, int n_in,
                              void* d_out, int out_size, void* d_ws, size_t ws_size,
                              hipStream_t stream) {
    (void)in_sizes; (void)n_in; (void)out_size; (void)ws_size;
    const float* x    = (const float*)d_in[0];
    const float* Ld   = (const float*)d_in[1];
    const float* Lu   = (const float*)d_in[2];
    const float* P    = (const float*)d_in[3];
    const float* W1   = (const float*)d_in[4];
    const float* W2   = (const float*)d_in[5];
    const float* W0   = (const float*)d_in[6];
    const float* att1 = (const float*)d_in[7];
    const float* att2 = (const float*)d_in[8];

    float* ws = (float*)d_ws;
    float* xwA1 = ws;                 // 131072 each
    float* xwB1 = ws + 131072;
    float* xwA2 = ws + 262144;
    float* xwB2 = ws + 393216;
    float* u1   = ws + 524288;        // xwA + L@xwB (fused)
    float* u2   = ws + 655360;
    float* a1   = ws + 786432;        // 4096 each
    float* b1   = ws + 790528;
    float* a2   = ws + 794624;
    float* b2   = ws + 798720;
    float* partial = ws + 802816;           // KS*131072 floats = 4 MB
    __hip_bfloat16* Bt = (__hip_bfloat16*)(ws + 1851392);   // 131072 bf16
    int2* csrv = (int2*)(ws + 1916928);     // 2*4096*128 int2 = 8 MB
    int*  cnt  = (int*)(ws + 4014080);      // 8192 ints

    k_prep<<<512, 256, 0, stream>>>(x, W1, W2, W0, att1, att2,
                                    xwA1, xwB1, xwA2, xwB2, a1, b1, a2, b2, Bt);
    k_csr2<<<NN / 2, 256, 0, stream>>>(Ld, Lu, csrv, cnt);
    k_pgemm<<<dim3(64, KS), 256, 0, stream>>>(P, (const ushort*)Bt, partial);
    k_gather2<<<dim3(NN / 4, 2), 256, 0, stream>>>(csrv, cnt, xwB1, xwB2,
                                                   xwA1, xwA2, a1, b1, a2, b2,
                                                   u1, u2);
    k_accum<<<NN / 4, 256, 0, stream>>>(csrv, cnt, u1, u2, partial,
                                        (float*)d_out);
}

// Round 9
// 224.026 us; speedup vs baseline: 1.0860x; 1.0573x over previous
//
#include <hip/hip_runtime.h>
#include <hip/hip_bf16.h>

#define NN 4096
#define CAP 128   // max nnz per row tracked (binomial mean 41, sd 6.4)
#define KS 8      // k-splits for P-GEMM

typedef __attribute__((ext_vector_type(8))) short bf16x8;
typedef __attribute__((ext_vector_type(4))) float f32x4;

__device__ __forceinline__ float lrelu(float v) { return v >= 0.f ? v : 0.2f * v; }

// fp32 -> bf16 bits, round-to-nearest-even (inputs are finite)
__device__ __forceinline__ ushort f2bu(float f) {
    unsigned u = __float_as_uint(f);
    return (ushort)((u + 0x7FFFu + ((u >> 16) & 1u)) >> 16);
}

// ---------------------------------------------------------------------------
// K1: xwA1=x@W1[0], xwB1=x@W1[1], xwA2=x@W2[0], xwB2=x@W2[1], v0=x@W0,
//     a/b attention vectors, Bt = (x@W0)^T as bf16 for the P-GEMM.
// ---------------------------------------------------------------------------
__global__ __launch_bounds__(256) void k_prep(
    const float* __restrict__ x,
    const float* __restrict__ W1, const float* __restrict__ W2,
    const float* __restrict__ W0,
    const float* __restrict__ att1, const float* __restrict__ att2,
    float* __restrict__ xwA1, float* __restrict__ xwB1,
    float* __restrict__ xwA2, float* __restrict__ xwB2,
    float* __restrict__ a1, float* __restrict__ b1,
    float* __restrict__ a2, float* __restrict__ b2,
    __hip_bfloat16* __restrict__ Bt)
{
    __shared__ float wl[5120];   // W1(2048) W2(2048) W0(1024)
    __shared__ float xs[256];    // 8 rows x 32
    const int t = threadIdx.x;
    for (int i = t; i < 2048; i += 256) { wl[i] = W1[i]; wl[2048 + i] = W2[i]; }
    for (int i = t; i < 1024; i += 256) wl[4096 + i] = W0[i];
    const int rowBase = blockIdx.x * 8;
    xs[t] = x[rowBase * 32 + t];
    __syncthreads();

    const int o = t & 31, r = t >> 5;
    const int row = rowBase + r;
    const float* xr = &xs[r * 32];
    float vA1 = 0.f, vB1 = 0.f, vA2 = 0.f, vB2 = 0.f, v0 = 0.f;
#pragma unroll
    for (int f = 0; f < 32; ++f) {
        const float xv = xr[f];
        vA1 += xv * wl[f * 32 + o];
        vB1 += xv * wl[1024 + f * 32 + o];
        vA2 += xv * wl[2048 + f * 32 + o];
        vB2 += xv * wl[3072 + f * 32 + o];
        v0  += xv * wl[4096 + f * 32 + o];
    }
    xwA1[row * 32 + o] = vA1;
    xwB1[row * 32 + o] = vB1;
    xwA2[row * 32 + o] = vA2;
    xwB2[row * 32 + o] = vB2;
    ((ushort*)Bt)[(size_t)o * NN + row] = f2bu(v0);

    float pa1 = vA1 * att1[o]      + vB1 * att1[32 + o];
    float pb1 = vA1 * att1[64 + o] + vB1 * att1[96 + o];
    float pa2 = vA2 * att2[o]      + vB2 * att2[32 + o];
    float pb2 = vA2 * att2[64 + o] + vB2 * att2[96 + o];
#pragma unroll
    for (int m = 1; m <= 16; m <<= 1) {
        pa1 += __shfl_xor(pa1, m); pb1 += __shfl_xor(pb1, m);
        pa2 += __shfl_xor(pa2, m); pb2 += __shfl_xor(pb2, m);
    }
    if (o == 0) { a1[row] = pa1; b1[row] = pb1; a2[row] = pa2; b2[row] = pb2; }
}

// ---------------------------------------------------------------------------
// K2 (k_scan3): block per (row, branch). Stream 16 KB row, two-phase ballot
// compaction into LDS, softmax over the list (b-gather L2-resident), write
// NORMALIZED weights into csrv (written once, final), fused y-gather:
// u[row] = xwA[row] + L[row,:] @ xwB. Deletes the former k_gather2.
// ---------------------------------------------------------------------------
__global__ __launch_bounds__(256) void k_scan3(
    const float* __restrict__ Ld, const float* __restrict__ Lu,
    const float* __restrict__ xwB1, const float* __restrict__ xwB2,
    const float* __restrict__ xwA1, const float* __restrict__ xwA2,
    const float* __restrict__ a1, const float* __restrict__ b1,
    const float* __restrict__ a2, const float* __restrict__ b2,
    int2* __restrict__ csrv, int* __restrict__ cntArr,
    float* __restrict__ u1, float* __restrict__ u2)
{
    const int row = blockIdx.x;
    const int br  = blockIdx.y;
    const float* L   = br ? Lu : Ld;
    const float* xwB = br ? xwB2 : xwB1;
    const float* xwA = br ? xwA2 : xwA1;
    const float* aA  = br ? a2 : a1;
    const float* bA  = br ? b2 : b1;
    int2* csrB = csrv + ((size_t)br * NN + row) * CAP;
    float* u   = br ? u2 : u1;

    __shared__ int   sidx[CAP];
    __shared__ float sval[CAP];
    __shared__ int   wcnt[16];
    __shared__ float red[256];
    __shared__ float rpart[8];
    const int t = threadIdx.x;
    const int lane = t & 63, w = t >> 6;

    // stream the row: 4 float4 in flight
    const float4* L4 = (const float4*)(L + (size_t)row * NN);
    float4 v[4];
#pragma unroll
    for (int it = 0; it < 4; ++it) v[it] = L4[it * 256 + t];

    const unsigned long long lt = (1ull << lane) - 1ull;

    // phase 1: per-(wave,iter) nonzero counts
    int tots[4];
#pragma unroll
    for (int it = 0; it < 4; ++it) {
        const unsigned long long m0 = __ballot(v[it].x != 0.f);
        const unsigned long long m1 = __ballot(v[it].y != 0.f);
        const unsigned long long m2 = __ballot(v[it].z != 0.f);
        const unsigned long long m3 = __ballot(v[it].w != 0.f);
        tots[it] = __popcll(m0) + __popcll(m1) + __popcll(m2) + __popcll(m3);
    }
    if (lane == 0) {
        int4 tv; tv.x = tots[0]; tv.y = tots[1]; tv.z = tots[2]; tv.w = tots[3];
        *(int4*)&wcnt[w * 4] = tv;
    }
    __syncthreads();

    // phase 2: prefix over 16 counts, compact into LDS
    const int4 ca = *(const int4*)&wcnt[0];
    const int4 cb = *(const int4*)&wcnt[4];
    const int4 cc = *(const int4*)&wcnt[8];
    const int4 cd = *(const int4*)&wcnt[12];
    const int cs[16] = {ca.x, ca.y, ca.z, ca.w, cb.x, cb.y, cb.z, cb.w,
                        cc.x, cc.y, cc.z, cc.w, cd.x, cd.y, cd.z, cd.w};
    int total = 0;
#pragma unroll
    for (int k2 = 0; k2 < 16; ++k2) total += cs[k2];
    int base = 0;
#pragma unroll
    for (int k2 = 0; k2 < 16; ++k2) base += (k2 < (w << 2)) ? cs[k2] : 0;

    const int cnt  = min(total, CAP);
    const int cp16 = min((cnt + 15) & ~15, CAP);

#pragma unroll
    for (int it = 0; it < 4; ++it) {
        const float vx = v[it].x, vy = v[it].y, vz = v[it].z, vw = v[it].w;
        const unsigned long long m0 = __ballot(vx != 0.f);
        const unsigned long long m1 = __ballot(vy != 0.f);
        const unsigned long long m2 = __ballot(vz != 0.f);
        const unsigned long long m3 = __ballot(vw != 0.f);
        const int p0 = __popcll(m0), p1 = __popcll(m1), p2 = __popcll(m2);
        const int c0 = (it * 256 + t) * 4;
        int s;
        s = base + __popcll(m0 & lt);
        if (vx != 0.f && s < CAP) { sidx[s] = c0;     sval[s] = vx; }
        s = base + p0 + __popcll(m1 & lt);
        if (vy != 0.f && s < CAP) { sidx[s] = c0 + 1; sval[s] = vy; }
        s = base + p0 + p1 + __popcll(m2 & lt);
        if (vz != 0.f && s < CAP) { sidx[s] = c0 + 2; sval[s] = vz; }
        s = base + p0 + p1 + p2 + __popcll(m3 & lt);
        if (vw != 0.f && s < CAP) { sidx[s] = c0 + 3; sval[s] = vw; }
        base += p0 + p1 + p2 + __popcll(m3);
    }
    // sentinel padding: safe idx 0, value 0
    if (t >= cnt && t < cp16) { sidx[t] = 0; sval[t] = 0.f; }
    __syncthreads();

    // --- softmax over the list: thread t handles slot t ---
    const float ai = aA[row];
    const int myidx = (t < cp16) ? sidx[t] : 0;
    const float e = (t < cnt) ? lrelu(ai + bA[myidx]) : -1e30f;
    float m = e;
#pragma unroll
    for (int mm = 1; mm <= 32; mm <<= 1) m = fmaxf(m, __shfl_xor(m, mm));
    if (lane == 0) rpart[w] = m;
    __syncthreads();
    m = fmaxf(fmaxf(rpart[0], rpart[1]), fmaxf(rpart[2], rpart[3]));
    const float wgt = (t < cnt) ? __expf(e - m) : 0.f;
    float ss = wgt;
#pragma unroll
    for (int mm = 1; mm <= 32; mm <<= 1) ss += __shfl_xor(ss, mm);
    if (lane == 0) rpart[4 + w] = ss;
    __syncthreads();
    const float ssum = rpart[4] + rpart[5] + rpart[6] + rpart[7];
    const float inv = (cnt > 0) ? 1.f / ssum : 0.f;
    if (t < cp16) { int2 eo; eo.x = myidx; eo.y = __float_as_int(wgt * inv); csrB[t] = eo; }
    if (t == 0) cntArr[br * NN + row] = cnt;

    // --- fused y-gather (raw values still in LDS) ---
    const int o = t & 31, g = t >> 5;
    float acc = 0.f;
    const int nPair = cp16 >> 4;     // 16 slots per batch: 2 per group
    if (nPair > 0) {
        float vA0 = sval[g],      vA1 = sval[g + 8];
        float xA0 = xwB[(size_t)sidx[g] * 32 + o];
        float xA1 = xwB[(size_t)sidx[g + 8] * 32 + o];
        for (int j = 1; j < nPair; ++j) {
            const int sB = g + 16 * j;
            const float vB0 = sval[sB],  vB1 = sval[sB + 8];
            const float xB0 = xwB[(size_t)sidx[sB] * 32 + o];
            const float xB1 = xwB[(size_t)sidx[sB + 8] * 32 + o];
            acc += vA0 * xA0 + vA1 * xA1;
            vA0 = vB0; xA0 = xB0; vA1 = vB1; xA1 = xB1;
        }
        acc += vA0 * xA0 + vA1 * xA1;
    }
    red[t] = acc;
    __syncthreads();
    if (t < 32) {
        float tot2 = 0.f;
#pragma unroll
        for (int g2 = 0; g2 < 8; ++g2) tot2 += red[g2 * 32 + t];
        u[(size_t)row * 32 + t] = tot2 + xwA[(size_t)row * 32 + t];
    }
}

// ---------------------------------------------------------------------------
// K3 (k_accum): wave per row. Pure weighted gather of U for both branches
// (weights pre-normalized in csrv), fold in KS partials, write d_out.
// ---------------------------------------------------------------------------
__global__ __launch_bounds__(256) void k_accum(
    const int2* __restrict__ csrv, const int* __restrict__ cntArr,
    const float* __restrict__ u1, const float* __restrict__ u2,
    const float* __restrict__ partial, float* __restrict__ outp)
{
    __shared__ int2 sle[4][2 * CAP];
    const int w = threadIdx.x >> 6, lane = threadIdx.x & 63;
    const int row = blockIdx.x * 4 + w;
    const int o = lane & 31, g = lane >> 5;
    int2* se = sle[w];
    float total = 0.f;

    int cp[2];
#pragma unroll
    for (int br = 0; br < 2; ++br) {
        const int cnt = cntArr[br * NN + row];
        cp[br] = min((cnt + 15) & ~15, CAP);
        const int2* ci = csrv + ((size_t)br * NN + row) * CAP;
        if (lane < cp[br])      se[br * CAP + lane]      = ci[lane];
        if (lane + 64 < cp[br]) se[br * CAP + lane + 64] = ci[lane + 64];
    }
    // wave-private LDS segment; same-wave ordering

#pragma unroll
    for (int br = 0; br < 2; ++br) {
        const float* U = br ? u2 : u1;
        float acc = 0.f;
        const int nb = cp[br] >> 3;
        for (int j = 0; j < nb; ++j) {
            float wv[4], uv[4];
#pragma unroll
            for (int q = 0; q < 4; ++q) {
                const int2 e = se[br * CAP + 8 * j + 2 * q + g];
                wv[q] = __int_as_float(e.y);
                uv[q] = U[(size_t)e.x * 32 + o];
            }
#pragma unroll
            for (int q = 0; q < 4; ++q) acc += wv[q] * uv[q];
        }
        acc += __shfl_xor(acc, 32);
        total += acc;
    }

    if (lane < 32) {
#pragma unroll
        for (int p = 0; p < KS; ++p)
            total += partial[(size_t)p * NN * 32 + (size_t)row * 32 + o];
        outp[(size_t)row * 32 + o] = total;
    }
}

// ---------------------------------------------------------------------------
// K4 (MFMA): partial[ks] = P[:, krange] @ B[krange, :]
// Block = 64 rows x 32 cols x 512 k; 4 chunks of 128 k, double-buffered LDS.
// ---------------------------------------------------------------------------
__global__ __launch_bounds__(256) void k_pgemm(
    const float* __restrict__ P, const ushort* __restrict__ Bt,
    float* __restrict__ partial)
{
    __shared__ ushort sA[2][16 * 64 * 8];
    __shared__ ushort sB[2][8 * 64 * 8];
    const int t = threadIdx.x;
    const int row0 = blockIdx.x * 64;
    const int ks = blockIdx.y;
    const float4*  P4  = (const float4*)P;
    const ushort4* Bt4 = (const ushort4*)Bt;

    const int lane = t & 63, w = t >> 6;

    f32x4 acc0 = {0.f, 0.f, 0.f, 0.f};
    f32x4 acc1 = {0.f, 0.f, 0.f, 0.f};

    auto stageA = [&](int c, int buf) {
        const int kc4 = (ks * 512 + c * 128) >> 2;
#pragma unroll
        for (int j = 0; j < 8; ++j) {
            const int i = t + 256 * j;
            const int row = i >> 5, q = i & 31;
            const float4 v = P4[(size_t)(row0 + row) * 1024 + kc4 + q];
            ushort4 u;
            u.x = f2bu(v.x); u.y = f2bu(v.y); u.z = f2bu(v.z); u.w = f2bu(v.w);
            const int wi = row >> 4, m = row & 15;
            const int kk = q >> 3, quad = (q >> 1) & 3, jj = q & 1;
            *(ushort4*)&sA[buf][(((wi * 4 + kk) * 64) + quad * 16 + m) * 8 + jj * 4] = u;
        }
    };
    auto stageB = [&](int c, int buf) {
        const int kc4 = (ks * 512 + c * 128) >> 2;
#pragma unroll
        for (int j = 0; j < 4; ++j) {
            const int i = t + 256 * j;
            const int o = i >> 5, q = i & 31;
            const ushort4 u = Bt4[(size_t)o * 1024 + kc4 + q];
            const int nt = o >> 4, n = o & 15;
            const int kk = q >> 3, quad = (q >> 1) & 3, jj = q & 1;
            *(ushort4*)&sB[buf][(((kk * 2 + nt) * 64) + quad * 16 + n) * 8 + jj * 4] = u;
        }
    };
    auto compute = [&](int buf) {
        const ushort* pa = &sA[buf][(w * 4) * 64 * 8 + lane * 8];
        const ushort* pb = &sB[buf][lane * 8];
#pragma unroll
        for (int kk = 0; kk < 4; ++kk) {
            const bf16x8 a  = *(const bf16x8*)(pa + kk * 512);
            const bf16x8 b0 = *(const bf16x8*)(pb + kk * 1024);
            const bf16x8 b1 = *(const bf16x8*)(pb + kk * 1024 + 512);
            acc0 = __builtin_amdgcn_mfma_f32_16x16x32_bf16(a, b0, acc0, 0, 0, 0);
            acc1 = __builtin_amdgcn_mfma_f32_16x16x32_bf16(a, b1, acc1, 0, 0, 0);
        }
    };

    stageA(0, 0); stageB(0, 0);
    __syncthreads();
    for (int c = 0; c < 4; ++c) {
        if (c < 3) { stageA(c + 1, (c + 1) & 1); stageB(c + 1, (c + 1) & 1); }
        compute(c & 1);
        __syncthreads();
    }

    const int m = lane & 15, quad = lane >> 4;
    float* out = partial + ((size_t)ks * NN + row0 + w * 16 + quad * 4) * 32;
#pragma unroll
    for (int r = 0; r < 4; ++r) {
        out[r * 32 + m]      = acc0[r];
        out[r * 32 + 16 + m] = acc1[r];
    }
}

extern "C" void kernel_launch(void* const* d_in, const int* in_sizes, int n_in,
                              void* d_out, int out_size, void* d_ws, size_t ws_size,
                              hipStream_t stream) {
    (void)in_sizes; (void)n_in; (void)out_size; (void)ws_size;
    const float* x    = (const float*)d_in[0];
    const float* Ld   = (const float*)d_in[1];
    const float* Lu   = (const float*)d_in[2];
    const float* P    = (const float*)d_in[3];
    const float* W1   = (const float*)d_in[4];
    const float* W2   = (const float*)d_in[5];
    const float* W0   = (const float*)d_in[6];
    const float* att1 = (const float*)d_in[7];
    const float* att2 = (const float*)d_in[8];

    float* ws = (float*)d_ws;
    float* xwA1 = ws;                 // 131072 each
    float* xwB1 = ws + 131072;
    float* xwA2 = ws + 262144;
    float* xwB2 = ws + 393216;
    float* u1   = ws + 524288;        // xwA + L@xwB (fused)
    float* u2   = ws + 655360;
    float* a1   = ws + 786432;        // 4096 each
    float* b1   = ws + 790528;
    float* a2   = ws + 794624;
    float* b2   = ws + 798720;
    float* partial = ws + 802816;           // KS*131072 floats = 4 MB
    __hip_bfloat16* Bt = (__hip_bfloat16*)(ws + 1851392);   // 131072 bf16
    int2* csrv = (int2*)(ws + 1916928);     // 2*4096*128 int2 = 8 MB
    int*  cnt  = (int*)(ws + 4014080);      // 8192 ints

    k_prep<<<512, 256, 0, stream>>>(x, W1, W2, W0, att1, att2,
                                    xwA1, xwB1, xwA2, xwB2, a1, b1, a2, b2, Bt);
    k_scan3<<<dim3(NN, 2), 256, 0, stream>>>(Ld, Lu, xwB1, xwB2, xwA1, xwA2,
                                             a1, b1, a2, b2, csrv, cnt, u1, u2);
    k_pgemm<<<dim3(64, KS), 256, 0, stream>>>(P, (const ushort*)Bt, partial);
    k_accum<<<NN / 4, 256, 0, stream>>>(csrv, cnt, u1, u2, partial,
                                        (float*)d_out);
}